// Round 1
// baseline (697.707 us; speedup 1.0000x reference)
//
#include <hip/hip_runtime.h>

// Soft-DTW forward, B=128, N=M=512, gamma=1.0, fp32.
// ROUND-10: 4-wave diagonal split. Previous best (326us bench / 207us
// dispatch) ran 1 wave/batch -> 128 waves on 1024 SIMDs (Occupancy 1.4%,
// VALUBusy 6.1% == ~49% busy on occupied SIMDs: issue-bound on one SIMD,
// 87.5% of the machine idle). Now: 256 threads/block = 4 waves on the
// CU's 4 SIMDs; wave w owns columns 128w..128w+127, lane owns 2 columns
// (was 8) -> ~4x less issue per SIMD per step.
//
// Cross-wave handoff (col 128w+127 -> 128w+128): parity-double-buffered
// LDS slot hs[w][s&1], one raw s_barrier per step with ONLY lgkmcnt(0)
// before it (NOT __syncthreads: vmcnt(0) would drain the 8-step global
// prefetch queue every step). diag is carried in a register (bd = bl),
// so per step: 1 broadcast ds_read (issued post-barrier, ~full interval
// of slack) + 1 predicated ds_write (issued right after nv1, long done
// by the barrier). Write parity U&1, read parity (U^1)&1 -> no hazard
// within an interval; reread of a slot is 2 barriers after its write.
//
// Renorm every 16 steps is BLOCK-uniform (handoff must stay in one
// block-FP frame): per-wave max via DPP row_shr/row_bcast ladder (~8
// VALU ops, replaces the 6x ds_bpermute butterfly), combined across
// waves through LDS mxs[4] + 1 barrier. The one handoff value read
// pre-renorm and consumed post-renorm (bl) is rescaled reader-side.
//
// Everything else is carried over verified from R9: exp-domain DP
// (E = e^-R, nv = w*(up+left+diag), w = exp2(-d*log2e)), untouched
// prefetch path (load -> buf regs, consumed 8/9 steps later, junk rows
// zeroed at CONSUMPTION from pure index math: junk <=> s - c >= jb+512),
// wave-uniform junk LHS (scalar s_add), output at the last cell.
// Slot algebra for the 2-col window: cell c at step s consumes the
// window loaded at step s-8-c; c=0 -> buf[P][U], c=1 -> buf[P][U-1]
// (U>=1) or buf[P^1][7] (U==0). JCHK templated off for qq<32 (junk
// first possible at s>=512).

#define BB 128
#define NN 512
#define MM 512
#define L2E 1.4426950408889634f
#define LN2 0.6931471805599453f

__device__ __forceinline__ int iclamp(int x, int lo, int hi) {
    return x < lo ? lo : (x > hi ? hi : x);
}

template<int CTRL>
__device__ __forceinline__ float dpp_fmax(float v) {
    // fmax(v, dpp(v)); lanes without a source keep old=v (or 0 if the
    // bound_ctrl polarity differs -- harmless: values are >= 0).
    const int s = __builtin_amdgcn_update_dpp(
        __float_as_int(v), __float_as_int(v), CTRL, 0xF, 0xF, false);
    return __builtin_fmaxf(v, __int_as_float(s));
}

// One DP anti-diagonal step for this wave's two columns. s = sbase + P*8 + U.
template<int P, int U, bool JCHK>
__device__ __forceinline__ void dostep(
    const float* __restrict__ Db, const int lane, const int w,
    const int jb, const int sbase, const int tq,
    float (&r1)[2], float (&r2)[2], float2 (&buf)[2][8],
    int& irow, float& sh, float& shprev, float& bl, float& bd,
    volatile float (*hs)[2])
{
    // prefetch window s+8 (consumed at s+8 (c=0) and s+9 (c=1)); loads
    // stay in flight across the barriers (no vmcnt at barrier).
    {
        const int r = iclamp(irow, 0, NN - 1);
        buf[P ^ 1][U] = *(const float2*)(Db + ((r << 9) + jb));
        irow += 1;
    }

    // c = 1 (inner column: all-local inputs)
    float nv1;
    {
        constexpr int par  = (U >= 1) ? P : (P ^ 1);
        constexpr int slot = (U >= 1) ? (U - 1) : 7;
        const float d = buf[par][slot].y;
        float wgt = __builtin_amdgcn_exp2f(-L2E * d);
        if (JCHK) {
            const bool junk = (sbase + (P * 8 + U - 1)) >= tq;  // i >= NN
            wgt = junk ? 0.0f : wgt;
        }
        nv1 = wgt * ((r1[1] + r1[0]) + r2[0]);
    }
    // publish boundary early (lane 63 -> hs[w][s&1]); readers use the
    // other parity this interval, so no pre-barrier hazard, and the
    // ds_write is long retired by the lgkmcnt(0) below.
    if (lane == 63) hs[w][U & 1] = nv1;

    // c = 0 (consumes intra-wave sh/shprev or cross-wave bl/bd)
    float nv0;
    {
        const float lf = (lane == 0) ? bl : sh;
        const float dg = (lane == 0) ? bd : shprev;
        const float d  = buf[P][U].x;
        float wgt = __builtin_amdgcn_exp2f(-L2E * d);
        if (JCHK) {
            const bool junk = (sbase + (P * 8 + U)) >= tq;
            wgt = junk ? 0.0f : wgt;
        }
        nv0 = wgt * ((r1[0] + lf) + dg);
    }

    r2[0] = r1[0]; r2[1] = r1[1];
    r1[0] = nv0;   r1[1] = nv1;
    bd = bl;

    // LDS visible, then barrier. lgkmcnt only: vmcnt untouched.
    asm volatile("s_waitcnt lgkmcnt(0)" ::: "memory");
    __builtin_amdgcn_s_barrier();
    asm volatile("" ::: "memory");

    // post-barrier: issue next step's cross-lane/cross-wave reads with
    // ~a full interval of slack before their c=0 consumption.
    shprev = sh;
    sh = __shfl_up(r1[1], 1, 64);
    if (w > 0) bl = hs[w - 1][U & 1];
}

// Block-uniform renorm: all 4 waves rescale by the same 2^-ex.
__device__ __forceinline__ void renorm4(
    const int lane, const int w,
    float (&r1)[2], float (&r2)[2], float& sh, float& shprev,
    float& bl, float& bd, float& gexp, volatile float* mxs)
{
    float m = __builtin_fmaxf(r1[0], r1[1]);
    m = dpp_fmax<0x111>(m);   // row_shr:1
    m = dpp_fmax<0x112>(m);   // row_shr:2
    m = dpp_fmax<0x114>(m);   // row_shr:4
    m = dpp_fmax<0x118>(m);   // row_shr:8  -> lane15 of each row16 = row max
    m = dpp_fmax<0x142>(m);   // row_bcast:15
    m = dpp_fmax<0x143>(m);   // row_bcast:31 -> lane 63 = wave max
    if (lane == 63) mxs[w] = m;
    asm volatile("s_waitcnt lgkmcnt(0)" ::: "memory");
    __builtin_amdgcn_s_barrier();
    asm volatile("" ::: "memory");
    const float m4 = __builtin_fmaxf(__builtin_fmaxf(mxs[0], mxs[1]),
                                     __builtin_fmaxf(mxs[2], mxs[3]));
    const int eb = (__float_as_int(m4) >> 23) & 255;
    const int ex = (eb > 0 && eb < 255) ? (eb - 127) : 0;  // 0/denorm/inf: hold
    const float rs = __int_as_float((127 - ex) << 23);     // exact 2^-ex
    r1[0] *= rs; r1[1] *= rs; r2[0] *= rs; r2[1] *= rs;
    sh *= rs; shprev *= rs;
    bl *= rs;   // handoff value read pre-renorm, consumed post-renorm
    bd *= rs;
    gexp += (float)ex;                                     // int-exact in fp32
}

#define S8(PP, JJ) \
    dostep<PP,0,JJ>(Db,lane,w,jb,sbase,tq,r1,r2,buf,irow,sh,shprev,bl,bd,hs); \
    dostep<PP,1,JJ>(Db,lane,w,jb,sbase,tq,r1,r2,buf,irow,sh,shprev,bl,bd,hs); \
    dostep<PP,2,JJ>(Db,lane,w,jb,sbase,tq,r1,r2,buf,irow,sh,shprev,bl,bd,hs); \
    dostep<PP,3,JJ>(Db,lane,w,jb,sbase,tq,r1,r2,buf,irow,sh,shprev,bl,bd,hs); \
    dostep<PP,4,JJ>(Db,lane,w,jb,sbase,tq,r1,r2,buf,irow,sh,shprev,bl,bd,hs); \
    dostep<PP,5,JJ>(Db,lane,w,jb,sbase,tq,r1,r2,buf,irow,sh,shprev,bl,bd,hs); \
    dostep<PP,6,JJ>(Db,lane,w,jb,sbase,tq,r1,r2,buf,irow,sh,shprev,bl,bd,hs); \
    dostep<PP,7,JJ>(Db,lane,w,jb,sbase,tq,r1,r2,buf,irow,sh,shprev,bl,bd,hs);

__launch_bounds__(256, 1)
__global__ void softdtw_wave4(const float* __restrict__ D, float* __restrict__ out) {
    const int b = blockIdx.x;
    const int tid = (int)threadIdx.x;
    const int w = tid >> 6;          // wave 0..3
    const int lane = tid & 63;
    const int jb = (w << 7) + (lane << 1);   // global column base (2 cols/lane)
    const int tq = jb + NN;          // junk threshold: s - c >= tq  <=>  i >= NN
    const float* __restrict__ Db = D + (size_t)b * (NN * MM);

    __shared__ float hsS[4][2];      // boundary handoff, parity dbuf
    __shared__ float mxsS[4];        // renorm wave maxes
    typedef volatile float vrow_t[2];
    vrow_t* hs = (vrow_t*)hsS;
    volatile float* mxs = (volatile float*)mxsS;

    if (tid < 8) ((float*)hsS)[tid] = 0.0f;
    if (tid < 4) mxsS[tid] = 0.0f;
    asm volatile("s_waitcnt lgkmcnt(0)" ::: "memory");
    __builtin_amdgcn_s_barrier();
    asm volatile("" ::: "memory");

    float r1[2] = {0.0f, 0.0f};
    float r2[2] = {0.0f, 0.0f};
    float2 buf[2][8];
    #pragma unroll
    for (int v = 0; v < 8; ++v) buf[1][v] = make_float2(0.0f, 0.0f); // read (fake cells) before first write
    // prologue: windows 0..7 (row v-jb, clamp handles <0)
    #pragma unroll
    for (int v = 0; v < 8; ++v) {
        const int r = iclamp(v - jb, 0, NN - 1);
        buf[0][v] = *(const float2*)(Db + ((r << 9) + jb));
    }
    int irow = 8 - jb;               // row of window s+8 at s=0
    float sh = 0.0f, shprev = 0.0f;
    float bl = 0.0f;                 // cross-wave left (wave 0: always 0)
    float bd = (w == 0) ? 1.0f : 0.0f; // x0 seed: E(R[0,0]=0)=1; becomes bl=0 after step 0
    float gexp = 0.0f;               // shared frame exponent (block-uniform)

    // steps 0..511: junk impossible (s < 512 <= tq) -> JCHK off
    #pragma unroll 1
    for (int qq = 0; qq < 32; ++qq) {
        const int sbase = qq << 4;
        renorm4(lane, w, r1, r2, sh, shprev, bl, bd, gexp, mxs);
        S8(0, false)
        S8(1, false)
    }
    // steps 512..1007
    #pragma unroll 1
    for (int qq = 32; qq < 63; ++qq) {
        const int sbase = qq << 4;
        renorm4(lane, w, r1, r2, sh, shprev, bl, bd, gexp, mxs);
        S8(0, true)
        S8(1, true)
    }
    // tail: steps 1008..1022 (15 steps)
    {
        const int sbase = 1008;
        renorm4(lane, w, r1, r2, sh, shprev, bl, bd, gexp, mxs);
        S8(0, true)
        dostep<1,0,true>(Db,lane,w,jb,sbase,tq,r1,r2,buf,irow,sh,shprev,bl,bd,hs);
        dostep<1,1,true>(Db,lane,w,jb,sbase,tq,r1,r2,buf,irow,sh,shprev,bl,bd,hs);
        dostep<1,2,true>(Db,lane,w,jb,sbase,tq,r1,r2,buf,irow,sh,shprev,bl,bd,hs);
        dostep<1,3,true>(Db,lane,w,jb,sbase,tq,r1,r2,buf,irow,sh,shprev,bl,bd,hs);
        dostep<1,4,true>(Db,lane,w,jb,sbase,tq,r1,r2,buf,irow,sh,shprev,bl,bd,hs);
        dostep<1,5,true>(Db,lane,w,jb,sbase,tq,r1,r2,buf,irow,sh,shprev,bl,bd,hs);
        dostep<1,6,true>(Db,lane,w,jb,sbase,tq,r1,r2,buf,irow,sh,shprev,bl,bd,hs);
    }

    // final cell (511,511): wave 3, lane 63, c=1 at step 1022.
    // E_true = r1[1] * 2^gexp;  R = -(log2(r1[1]) + gexp) * ln2
    if (w == 3 && lane == 63) {
        out[b] = -(__builtin_amdgcn_logf(r1[1]) + gexp) * LN2;
    }
}

extern "C" void kernel_launch(void* const* d_in, const int* in_sizes, int n_in,
                              void* d_out, int out_size, void* d_ws, size_t ws_size,
                              hipStream_t stream) {
    const float* D = (const float*)d_in[0];
    float* out = (float*)d_out;
    softdtw_wave4<<<BB, 256, 0, stream>>>(D, out);
}

// Round 2
// 395.858 us; speedup vs baseline: 1.7625x; 1.7625x over previous
//
#include <hip/hip_runtime.h>

// Soft-DTW forward, B=128, N=M=512, gamma=1.0, fp32.
// ROUND-11: R10 (4-wave split) post-mortem fix. R10 regressed 207->568us
// because the cross-wave handoff used VOLATILE LDS accesses: AMDGPU's
// memory legalizer inserts s_waitcnt vmcnt(0) lgkmcnt(0) before every
// volatile op -> the 16-deep global prefetch queue was drained EVERY
// step -> full gather latency (~1150 cyc/step) exposed every step (the
// R3/R8 failure mode through a third back door; VALUBusy fell to 3.5%).
// Fix: plain (non-volatile) LDS accesses. Ordering/visibility for the
// handoff needs only: ds_write -> s_waitcnt lgkmcnt(0) -> s_barrier ->
// ds_read, which is already explicit via inline asm; the "memory"
// clobbers pin program order so the compiler neither caches nor hoists
// the LDS reads across barriers. vmcnt is never drained in the loop.
//
// Structure (unchanged from R10, verified correct there: absmax=0):
// 256 threads/block = 4 waves on the CU's 4 SIMDs; wave w owns columns
// 128w..128w+127, lane owns 2 columns. Cross-wave handoff via parity-
// double-buffered LDS slot hs[w][s&1]; diag carried in a register
// (bd = bl). Write parity U&1, read parity (U^1)&1 -> no intra-interval
// hazard; a slot is re-read 2 barriers after its write.
//
// Renorm every 16 steps is BLOCK-uniform (handoff shares one block-FP
// frame): per-wave max via DPP row_shr/row_bcast ladder, combined
// across waves through LDS mxs[4] + 1 barrier; bl/bd rescaled
// reader-side.
//
// Exp-domain DP (E = e^-R, nv = w*(up+left+diag), w = exp2(-d*log2e)),
// untouched prefetch path (load -> buf regs, consumed 8/9 steps later,
// junk rows zeroed at CONSUMPTION from pure index math: junk <=>
// s - c >= jb+512). Slot algebra for the 2-col window: cell c at step s
// consumes the window loaded at step s-8-c; c=0 -> buf[P][U], c=1 ->
// buf[P][U-1] (U>=1) or buf[P^1][7] (U==0). JCHK off for qq<32.

#define BB 128
#define NN 512
#define MM 512
#define L2E 1.4426950408889634f
#define LN2 0.6931471805599453f

__device__ __forceinline__ int iclamp(int x, int lo, int hi) {
    return x < lo ? lo : (x > hi ? hi : x);
}

template<int CTRL>
__device__ __forceinline__ float dpp_fmax(float v) {
    // fmax(v, dpp(v)); lanes without a source keep old=v.
    const int s = __builtin_amdgcn_update_dpp(
        __float_as_int(v), __float_as_int(v), CTRL, 0xF, 0xF, false);
    return __builtin_fmaxf(v, __int_as_float(s));
}

// One DP anti-diagonal step for this wave's two columns. s = sbase + P*8 + U.
template<int P, int U, bool JCHK>
__device__ __forceinline__ void dostep(
    const float* __restrict__ Db, const int lane, const int w,
    const int jb, const int sbase, const int tq,
    float (&r1)[2], float (&r2)[2], float2 (&buf)[2][8],
    int& irow, float& sh, float& shprev, float& bl, float& bd,
    float (*hs)[2])
{
    // prefetch window s+8 (consumed at s+8 (c=0) and s+9 (c=1)); loads
    // stay in flight across the barriers (no vmcnt drain anywhere).
    {
        const int r = iclamp(irow, 0, NN - 1);
        buf[P ^ 1][U] = *(const float2*)(Db + ((r << 9) + jb));
        irow += 1;
    }

    // c = 1 (inner column: all-local inputs)
    float nv1;
    {
        constexpr int par  = (U >= 1) ? P : (P ^ 1);
        constexpr int slot = (U >= 1) ? (U - 1) : 7;
        const float d = buf[par][slot].y;
        float wgt = __builtin_amdgcn_exp2f(-L2E * d);
        if (JCHK) {
            const bool junk = (sbase + (P * 8 + U - 1)) >= tq;  // i >= NN
            wgt = junk ? 0.0f : wgt;
        }
        nv1 = wgt * ((r1[1] + r1[0]) + r2[0]);
    }
    // publish boundary early (lane 63 -> hs[w][s&1]); readers use the
    // other parity this interval, so no pre-barrier hazard, and the
    // ds_write is retired by the lgkmcnt(0) below.
    if (lane == 63) hs[w][U & 1] = nv1;

    // c = 0 (consumes intra-wave sh/shprev or cross-wave bl/bd)
    float nv0;
    {
        const float lf = (lane == 0) ? bl : sh;
        const float dg = (lane == 0) ? bd : shprev;
        const float d  = buf[P][U].x;
        float wgt = __builtin_amdgcn_exp2f(-L2E * d);
        if (JCHK) {
            const bool junk = (sbase + (P * 8 + U)) >= tq;
            wgt = junk ? 0.0f : wgt;
        }
        nv0 = wgt * ((r1[0] + lf) + dg);
    }

    r2[0] = r1[0]; r2[1] = r1[1];
    r1[0] = nv0;   r1[1] = nv1;
    bd = bl;

    // LDS visible, then barrier. lgkmcnt only: vmcnt untouched.
    asm volatile("s_waitcnt lgkmcnt(0)" ::: "memory");
    __builtin_amdgcn_s_barrier();
    asm volatile("" ::: "memory");

    // post-barrier: issue next step's cross-lane/cross-wave reads with
    // ~a full interval of slack before their c=0 consumption.
    shprev = sh;
    sh = __shfl_up(r1[1], 1, 64);
    if (w > 0) bl = hs[w - 1][U & 1];
}

// Block-uniform renorm: all 4 waves rescale by the same 2^-ex.
__device__ __forceinline__ void renorm4(
    const int lane, const int w,
    float (&r1)[2], float (&r2)[2], float& sh, float& shprev,
    float& bl, float& bd, float& gexp, float* mxs)
{
    float m = __builtin_fmaxf(r1[0], r1[1]);
    m = dpp_fmax<0x111>(m);   // row_shr:1
    m = dpp_fmax<0x112>(m);   // row_shr:2
    m = dpp_fmax<0x114>(m);   // row_shr:4
    m = dpp_fmax<0x118>(m);   // row_shr:8  -> lane15 of each row16 = row max
    m = dpp_fmax<0x142>(m);   // row_bcast:15
    m = dpp_fmax<0x143>(m);   // row_bcast:31 -> lane 63 = wave max
    if (lane == 63) mxs[w] = m;
    asm volatile("s_waitcnt lgkmcnt(0)" ::: "memory");
    __builtin_amdgcn_s_barrier();
    asm volatile("" ::: "memory");
    const float m4 = __builtin_fmaxf(__builtin_fmaxf(mxs[0], mxs[1]),
                                     __builtin_fmaxf(mxs[2], mxs[3]));
    const int eb = (__float_as_int(m4) >> 23) & 255;
    const int ex = (eb > 0 && eb < 255) ? (eb - 127) : 0;  // 0/denorm/inf: hold
    const float rs = __int_as_float((127 - ex) << 23);     // exact 2^-ex
    r1[0] *= rs; r1[1] *= rs; r2[0] *= rs; r2[1] *= rs;
    sh *= rs; shprev *= rs;
    bl *= rs;   // handoff value read pre-renorm, consumed post-renorm
    bd *= rs;
    gexp += (float)ex;                                     // int-exact in fp32
}

#define S8(PP, JJ) \
    dostep<PP,0,JJ>(Db,lane,w,jb,sbase,tq,r1,r2,buf,irow,sh,shprev,bl,bd,hs); \
    dostep<PP,1,JJ>(Db,lane,w,jb,sbase,tq,r1,r2,buf,irow,sh,shprev,bl,bd,hs); \
    dostep<PP,2,JJ>(Db,lane,w,jb,sbase,tq,r1,r2,buf,irow,sh,shprev,bl,bd,hs); \
    dostep<PP,3,JJ>(Db,lane,w,jb,sbase,tq,r1,r2,buf,irow,sh,shprev,bl,bd,hs); \
    dostep<PP,4,JJ>(Db,lane,w,jb,sbase,tq,r1,r2,buf,irow,sh,shprev,bl,bd,hs); \
    dostep<PP,5,JJ>(Db,lane,w,jb,sbase,tq,r1,r2,buf,irow,sh,shprev,bl,bd,hs); \
    dostep<PP,6,JJ>(Db,lane,w,jb,sbase,tq,r1,r2,buf,irow,sh,shprev,bl,bd,hs); \
    dostep<PP,7,JJ>(Db,lane,w,jb,sbase,tq,r1,r2,buf,irow,sh,shprev,bl,bd,hs);

__launch_bounds__(256, 1)
__global__ void softdtw_wave4(const float* __restrict__ D, float* __restrict__ out) {
    const int b = blockIdx.x;
    const int tid = (int)threadIdx.x;
    const int w = tid >> 6;          // wave 0..3
    const int lane = tid & 63;
    const int jb = (w << 7) + (lane << 1);   // global column base (2 cols/lane)
    const int tq = jb + NN;          // junk threshold: s - c >= tq  <=>  i >= NN
    const float* __restrict__ Db = D + (size_t)b * (NN * MM);

    __shared__ float hsS[4][2];      // boundary handoff, parity dbuf
    __shared__ float mxsS[4];        // renorm wave maxes
    float (*hs)[2] = hsS;
    float* mxs = mxsS;

    if (tid < 8) ((float*)hsS)[tid] = 0.0f;
    if (tid < 4) mxsS[tid] = 0.0f;
    asm volatile("s_waitcnt lgkmcnt(0)" ::: "memory");
    __builtin_amdgcn_s_barrier();
    asm volatile("" ::: "memory");

    float r1[2] = {0.0f, 0.0f};
    float r2[2] = {0.0f, 0.0f};
    float2 buf[2][8];
    #pragma unroll
    for (int v = 0; v < 8; ++v) buf[1][v] = make_float2(0.0f, 0.0f); // read (fake cells) before first write
    // prologue: windows 0..7 (row v-jb, clamp handles <0)
    #pragma unroll
    for (int v = 0; v < 8; ++v) {
        const int r = iclamp(v - jb, 0, NN - 1);
        buf[0][v] = *(const float2*)(Db + ((r << 9) + jb));
    }
    int irow = 8 - jb;               // row of window s+8 at s=0
    float sh = 0.0f, shprev = 0.0f;
    float bl = 0.0f;                 // cross-wave left (wave 0: always 0)
    float bd = (w == 0) ? 1.0f : 0.0f; // x0 seed: E(R[0,0]=0)=1; becomes bl=0 after step 0
    float gexp = 0.0f;               // shared frame exponent (block-uniform)

    // steps 0..511: junk impossible (s < 512 <= tq) -> JCHK off
    #pragma unroll 1
    for (int qq = 0; qq < 32; ++qq) {
        const int sbase = qq << 4;
        renorm4(lane, w, r1, r2, sh, shprev, bl, bd, gexp, mxs);
        S8(0, false)
        S8(1, false)
    }
    // steps 512..1007
    #pragma unroll 1
    for (int qq = 32; qq < 63; ++qq) {
        const int sbase = qq << 4;
        renorm4(lane, w, r1, r2, sh, shprev, bl, bd, gexp, mxs);
        S8(0, true)
        S8(1, true)
    }
    // tail: steps 1008..1022 (15 steps)
    {
        const int sbase = 1008;
        renorm4(lane, w, r1, r2, sh, shprev, bl, bd, gexp, mxs);
        S8(0, true)
        dostep<1,0,true>(Db,lane,w,jb,sbase,tq,r1,r2,buf,irow,sh,shprev,bl,bd,hs);
        dostep<1,1,true>(Db,lane,w,jb,sbase,tq,r1,r2,buf,irow,sh,shprev,bl,bd,hs);
        dostep<1,2,true>(Db,lane,w,jb,sbase,tq,r1,r2,buf,irow,sh,shprev,bl,bd,hs);
        dostep<1,3,true>(Db,lane,w,jb,sbase,tq,r1,r2,buf,irow,sh,shprev,bl,bd,hs);
        dostep<1,4,true>(Db,lane,w,jb,sbase,tq,r1,r2,buf,irow,sh,shprev,bl,bd,hs);
        dostep<1,5,true>(Db,lane,w,jb,sbase,tq,r1,r2,buf,irow,sh,shprev,bl,bd,hs);
        dostep<1,6,true>(Db,lane,w,jb,sbase,tq,r1,r2,buf,irow,sh,shprev,bl,bd,hs);
    }

    // final cell (511,511): wave 3, lane 63, c=1 at step 1022.
    // E_true = r1[1] * 2^gexp;  R = -(log2(r1[1]) + gexp) * ln2
    if (w == 3 && lane == 63) {
        out[b] = -(__builtin_amdgcn_logf(r1[1]) + gexp) * LN2;
    }
}

extern "C" void kernel_launch(void* const* d_in, const int* in_sizes, int n_in,
                              void* d_out, int out_size, void* d_ws, size_t ws_size,
                              hipStream_t stream) {
    const float* D = (const float*)d_in[0];
    float* out = (float*)d_out;
    softdtw_wave4<<<BB, 256, 0, stream>>>(D, out);
}

// Round 3
// 377.227 us; speedup vs baseline: 1.8496x; 1.0494x over previous
//
#include <hip/hip_runtime.h>

// Soft-DTW forward, B=128, N=M=512, gamma=1.0, fp32.
// ROUND-12: skewed 4-wave pipeline. R11 (lockstep 4-wave, barrier/step)
// ran 610 cy/step vs single-wave 486: the per-step lgkmcnt+s_barrier+
// post-barrier LDS-latency chain (~220cy) exceeded the 4x issue savings
// (~90cy). Fix: wave w runs 16 diagonals BEHIND wave w-1 (skew = renorm
// period). Boundary handoff via 64-slot LDS ring per boundary:
// wave w-1 writes lane-63 nv1 of local step s to ring[w-1][s&63]; wave w
// reads slot s (consumed as left at s+1, diag at s+2 via bl/bd register
// carry) one interval later. ONE barrier per 16-step interval:
//   - reader interval m reads exactly the slots written in writer
//     interval m-1 (>=1 barrier between write and read);
//   - a slot is rewritten 64 steps after its write (>=2 barriers after
//     the read). Both hazards barrier-protected; verified by algebra:
//     writer (wave w-1) at global interval k computes local steps
//     16(k-w)+16+j; reader (wave w) at interval k computes 16(k-w)+j
//     and end-of-step-s reads slot s.
// Renorm every 16 steps is now PER-WAVE (DPP row_shr/bcast ladder +
// readlane63, no LDS, no barrier). Each ring chunk is written under one
// writer frame; writer publishes gexp per interval (gx[w][k&1], global-k
// parity), reader converts chunk values with one exact pow2 scale
// 2^(gx_pub - gexp_reader) (1 off-chain mul per bl read). The bl/bd that
// cross a renorm boundary get the renorm rs on top — exact composition.
// Pipeline fill/drain: 67 intervals (1072 phases) vs 64 (+5%).
//
// Carried over verified from R11 (absmax=0): exp-domain DP (E=e^-R,
// nv = w*(up+left+diag), w=exp2(-d*log2e)); untouched prefetch (load ->
// buf regs, consumed 8/9 steps later, vmcnt NEVER drained in the loop —
// only lgkmcnt(0) before each per-interval barrier); junk rows zeroed at
// consumption from index math (junk <=> s-c >= jb+512), now always-on;
// slot algebra: cell c at step s consumes window loaded at s-8-c;
// c=0 -> buf[P][U], c=1 -> buf[P][U-1] (U>=1) or buf[P^1][7] (U==0).

#define BB 128
#define NN 512
#define MM 512
#define L2E 1.4426950408889634f
#define LN2 0.6931471805599453f

__device__ __forceinline__ int iclamp(int x, int lo, int hi) {
    return x < lo ? lo : (x > hi ? hi : x);
}

template<int CTRL>
__device__ __forceinline__ float dpp_fmax(float v) {
    const int s = __builtin_amdgcn_update_dpp(
        __float_as_int(v), __float_as_int(v), CTRL, 0xF, 0xF, false);
    return __builtin_fmaxf(v, __int_as_float(s));
}

// One DP step for this wave's two columns. Local step s = sbase + P*8 + U.
template<int P, int U>
__device__ __forceinline__ void dostep(
    const float* __restrict__ Db, const int lane, const int w,
    const int jb, const int sbase, const int tq,
    float (&r1)[2], float (&r2)[2], float2 (&buf)[2][8],
    int& irow, float& sh, float& shprev, float& bl, float& bd,
    float* ring, const float scale)
{
    // prefetch window s+8; stays in flight (vmcnt untouched by barriers)
    {
        const int r = iclamp(irow, 0, NN - 1);
        buf[P ^ 1][U] = *(const float2*)(Db + ((r << 9) + jb));
        irow += 1;
    }
    const int s = sbase + P * 8 + U;   // wave-uniform

    // c = 1 (inner column: all-local inputs)
    float nv1;
    {
        constexpr int par  = (U >= 1) ? P : (P ^ 1);
        constexpr int slot = (U >= 1) ? (U - 1) : 7;
        const float d = buf[par][slot].y;
        float wgt = __builtin_amdgcn_exp2f(-L2E * d);
        const bool junk = (s - 1) >= tq;           // col jb+1: i = s-1-jb >= 512
        wgt = junk ? 0.0f : wgt;
        nv1 = wgt * ((r1[1] + r1[0]) + r2[0]);
    }
    // publish boundary into the ring (read by wave w+1 next interval)
    if (lane == 63 && w < 3) ring[(w << 6) + (s & 63)] = nv1;

    // c = 0 (consumes intra-wave sh/shprev or cross-wave bl/bd)
    float nv0;
    {
        const float lf = (lane == 0) ? bl : sh;
        const float dg = (lane == 0) ? bd : shprev;
        const float d  = buf[P][U].x;
        float wgt = __builtin_amdgcn_exp2f(-L2E * d);
        const bool junk = s >= tq;                 // col jb: i = s-jb >= 512
        wgt = junk ? 0.0f : wgt;
        nv0 = wgt * ((r1[0] + lf) + dg);
    }

    r2[0] = r1[0]; r2[1] = r1[1];
    r1[0] = nv0;   r1[1] = nv1;
    bd = bl;
    shprev = sh;
    sh = __shfl_up(r1[1], 1, 64);                  // consumed next step: full slack
    // read next bl: writer's nv1(s), written LAST interval (barrier-safe);
    // frame-converted with this interval's scale. Consumed next step.
    if (w > 0) bl = ring[((w - 1) << 6) + (s & 63)] * scale;
}

// Per-wave renorm: rescale own state by 2^-ex, ex = exponent of wave max.
__device__ __forceinline__ void renorm_local(
    float (&r1)[2], float (&r2)[2], float& sh, float& shprev,
    float& bl, float& bd, float& gexp)
{
    float m = __builtin_fmaxf(r1[0], r1[1]);
    m = dpp_fmax<0x111>(m);   // row_shr:1
    m = dpp_fmax<0x112>(m);   // row_shr:2
    m = dpp_fmax<0x114>(m);   // row_shr:4
    m = dpp_fmax<0x118>(m);   // row_shr:8
    m = dpp_fmax<0x142>(m);   // row_bcast:15
    m = dpp_fmax<0x143>(m);   // row_bcast:31 -> lane 63 = wave max
    const int mb = __builtin_amdgcn_readlane(__float_as_int(m), 63);
    const int eb = (mb >> 23) & 255;
    const int ex = (eb > 0 && eb < 255) ? (eb - 127) : 0;  // 0/denorm/inf: hold
    const float rs = __int_as_float((127 - ex) << 23);     // exact 2^-ex
    r1[0] *= rs; r1[1] *= rs; r2[0] *= rs; r2[1] *= rs;
    sh *= rs; shprev *= rs;
    bl *= rs;   // interval-crossing handoff values: compose frames exactly
    bd *= rs;
    gexp += (float)ex;                                     // int-exact in fp32
}

#define S8(PP) \
    dostep<PP,0>(Db,lane,w,jb,sbase,tq,r1,r2,buf,irow,sh,shprev,bl,bd,ring,scale); \
    dostep<PP,1>(Db,lane,w,jb,sbase,tq,r1,r2,buf,irow,sh,shprev,bl,bd,ring,scale); \
    dostep<PP,2>(Db,lane,w,jb,sbase,tq,r1,r2,buf,irow,sh,shprev,bl,bd,ring,scale); \
    dostep<PP,3>(Db,lane,w,jb,sbase,tq,r1,r2,buf,irow,sh,shprev,bl,bd,ring,scale); \
    dostep<PP,4>(Db,lane,w,jb,sbase,tq,r1,r2,buf,irow,sh,shprev,bl,bd,ring,scale); \
    dostep<PP,5>(Db,lane,w,jb,sbase,tq,r1,r2,buf,irow,sh,shprev,bl,bd,ring,scale); \
    dostep<PP,6>(Db,lane,w,jb,sbase,tq,r1,r2,buf,irow,sh,shprev,bl,bd,ring,scale); \
    dostep<PP,7>(Db,lane,w,jb,sbase,tq,r1,r2,buf,irow,sh,shprev,bl,bd,ring,scale);

__launch_bounds__(256, 1)
__global__ void softdtw_skew4(const float* __restrict__ D, float* __restrict__ out) {
    const int b = blockIdx.x;
    const int tid = (int)threadIdx.x;
    const int w = tid >> 6;                  // wave 0..3
    const int lane = tid & 63;
    const int jb = (w << 7) + (lane << 1);   // global column base (2 cols/lane)
    const int tq = jb + NN;                  // junk: s - c >= tq  <=>  i >= NN
    const float* __restrict__ Db = D + (size_t)b * (NN * MM);

    __shared__ float ringS[3 * 64];          // boundary rings (w=0..2)
    __shared__ float gxS[8];                 // published frames, parity by global k
    float* ring = ringS;
    float* gx = gxS;

    if (tid < 3 * 64) ringS[tid] = 0.0f;     // safety init (never read unwritten)
    if (tid < 8) gxS[tid] = 0.0f;

    float r1[2] = {0.0f, 0.0f};
    float r2[2] = {0.0f, 0.0f};
    float2 buf[2][8];
    #pragma unroll
    for (int v = 0; v < 8; ++v) buf[1][v] = make_float2(0.0f, 0.0f); // fake cells pre-write
    // prologue: prefetch windows 0..7 (row v-jb, clamp handles <0)
    #pragma unroll
    for (int v = 0; v < 8; ++v) {
        const int r = iclamp(v - jb, 0, NN - 1);
        buf[0][v] = *(const float2*)(Db + ((r << 9) + jb));
    }
    int irow = 8 - jb;                       // row of window s+8 at s=0
    float sh = 0.0f, shprev = 0.0f;
    float bl = 0.0f;                         // left handoff (wave 0: always 0)
    float bd = (w == 0) ? 1.0f : 0.0f;       // seed E(R[0,0]=0)=1 at (0,0); then 0
    float gexp = 0.0f;                       // per-wave frame exponent

    // 67 global intervals; wave w active for k in [w, w+63] (local steps
    // sbase = 16(k-w)). One barrier per interval; lgkmcnt only (no vmcnt
    // drain). Inactive waves just hit the barrier.
    #pragma unroll 1
    for (int k = 0; k < 67; ++k) {
        asm volatile("s_waitcnt lgkmcnt(0)" ::: "memory");
        __builtin_amdgcn_s_barrier();
        asm volatile("" ::: "memory");
        const int kw = k - w;
        if (kw < 0 || kw > 63) continue;
        const int sbase = kw << 4;
        renorm_local(r1, r2, sh, shprev, bl, bd, gexp);
        if (lane == 63 && w < 3) gx[(w << 1) + (k & 1)] = gexp;
        float scale = 1.0f;
        if (w > 0) {
            // writer's frame for the chunk read this interval (published
            // at writer's global interval k-1)
            const float gxp = gx[((w - 1) << 1) + ((k - 1) & 1)];
            int dlt = (int)(gxp - gexp);     // both int-exact in fp32
            dlt = iclamp(dlt, -126, 126);
            scale = __int_as_float((127 + dlt) << 23);  // exact 2^dlt
        }
        if (kw < 63) {
            S8(0)
            S8(1)
        } else {
            // tail interval: local steps 1008..1022 (15 steps)
            S8(0)
            dostep<1,0>(Db,lane,w,jb,sbase,tq,r1,r2,buf,irow,sh,shprev,bl,bd,ring,scale);
            dostep<1,1>(Db,lane,w,jb,sbase,tq,r1,r2,buf,irow,sh,shprev,bl,bd,ring,scale);
            dostep<1,2>(Db,lane,w,jb,sbase,tq,r1,r2,buf,irow,sh,shprev,bl,bd,ring,scale);
            dostep<1,3>(Db,lane,w,jb,sbase,tq,r1,r2,buf,irow,sh,shprev,bl,bd,ring,scale);
            dostep<1,4>(Db,lane,w,jb,sbase,tq,r1,r2,buf,irow,sh,shprev,bl,bd,ring,scale);
            dostep<1,5>(Db,lane,w,jb,sbase,tq,r1,r2,buf,irow,sh,shprev,bl,bd,ring,scale);
            dostep<1,6>(Db,lane,w,jb,sbase,tq,r1,r2,buf,irow,sh,shprev,bl,bd,ring,scale);
        }
    }

    // final cell (511,511): wave 3, lane 63, c=1 at local step 1022.
    // E_true = r1[1] * 2^gexp;  R = -(log2(r1[1]) + gexp) * ln2
    if (w == 3 && lane == 63) {
        out[b] = -(__builtin_amdgcn_logf(r1[1]) + gexp) * LN2;
    }
}

extern "C" void kernel_launch(void* const* d_in, const int* in_sizes, int n_in,
                              void* d_out, int out_size, void* d_ws, size_t ws_size,
                              hipStream_t stream) {
    const float* D = (const float*)d_in[0];
    float* out = (float*)d_out;
    softdtw_skew4<<<BB, 256, 0, stream>>>(D, out);
}

// Round 5
// 328.598 us; speedup vs baseline: 2.1233x; 1.1480x over previous
//
#include <hip/hip_runtime.h>

// Soft-DTW forward, B=128, N=M=512, gamma=1.0, fp32.
// ROUND-14: hardened de-scratch of the skewed 4-wave pipeline.
// R11/R12 post-mortem: VGPR_Count 24/36 < the >=58 needed -> buf[2][8]
// was in SCRATCH (asm "memory" clobbers defeated SROA; every step paid
// scratch store+load+wait ~450cy, insensitive to barrier frequency).
// R9 (no clobbers, VGPR=92) kept regs — the proof. R13 (first attempt
// at this fix) failed at the container; suspect float4-struct asm
// operands (not a native vector -> constraint "v" can fail) and/or the
// 63-lane dummy-address ds_write. Both removed here:
//   - f32x4 = ext_vector_type(4) for all b128 asm operands;
//   - ZERO per-step LDS ops: lane63 accumulates its 16 boundary values
//     in statically-indexed regs hist[16], publishes once per interval
//     (4x ds_write_b128 + 1x ds_write_b32 frame) in one divergent
//     lane63 branch. The 16-step body is pure VALU + 1 plain pipelined
//     global_load_dwordx2 per step (the R9-proven path).
// Structure (verified absmax=0 in R12): wave w runs 16 diagonals behind
// wave w-1 (skew = renorm period). 64-slot LDS ring per boundary; ONE
// "s_waitcnt lgkmcnt(0); s_barrier" volatile asm per 16-step interval
// for ALL waves (balanced, vmcnt never drained). Reader interval k
// batch-reads (4x ds_read_b128 + gexp + lgkmcnt(0), one volatile asm)
// the chunk the writer published at interval k-1; volatile asms keep
// mutual program order, so write -> barrier -> read needs no compiler
// memory fence and no clobbers.
// Hazards (>=1 barrier between conflicting ops, re-verified):
//   write(end of k-1) -> barrier(k) -> read(top of k) -> barrier(k+1)
//   -> earliest same-slot rewrite (ring: 4 intervals; gx parity: k+1).
// Frames: per-wave renorm every 16 steps (DPP ladder + readlane63, no
// LDS); writer publishes its post-renorm gexp with the chunk; reader
// converts with one exact pow2 scale; w==0 / garbage killed by SELECT
// (never multiply: NaN*0=NaN). Interval-crossing bl/bd get the renorm
// rs on top — exact composition.
// Carried over verified: exp-domain DP (E=e^-R, nv=w*(up+left+diag),
// w=exp2(-d*log2e)); 8-deep float2 prefetch (plain loads, consumed 8/9
// steps later); junk-at-consume (junk <=> s-c >= jb+512); slot algebra
// c=0 -> buf[P][U], c=1 -> buf[P][U-1] (U>=1) or buf[P^1][7] (U==0);
// DPP wave_shr:1 for the intra-wave handoff; 67 intervals (+5% fill).

#define BB 128
#define NN 512
#define MM 512
#define L2E 1.4426950408889634f
#define LN2 0.6931471805599453f

typedef float f32x4 __attribute__((ext_vector_type(4)));

__device__ __forceinline__ int iclamp(int x, int lo, int hi) {
    return x < lo ? lo : (x > hi ? hi : x);
}

template<int CTRL>
__device__ __forceinline__ float dpp_fmax(float v) {
    const int s = __builtin_amdgcn_update_dpp(
        __float_as_int(v), __float_as_int(v), CTRL, 0xF, 0xF, false);
    return __builtin_fmaxf(v, __int_as_float(s));
}

// lane k <- lane k-1 (whole wave, wave_shr:1), VALU-speed; lane 0 keeps
// its old value (unused there: lane 0's c=0 selects bl, not sh).
__device__ __forceinline__ float dpp_shr1(float v) {
    const int s = __builtin_amdgcn_update_dpp(
        __float_as_int(v), __float_as_int(v), 0x138, 0xF, 0xF, false);
    return __int_as_float(s);
}

// One DP step for this wave's two columns. Local step s = sbase + P*8 + U.
// Body is asm-free and LDS-free: pure VALU + 1 plain global float2 load.
template<int P, int U>
__device__ __forceinline__ void dostep(
    const float* __restrict__ Db, const int lane, const int jb,
    const int sbase, const int tq,
    float (&r1)[2], float (&r2)[2], float2 (&buf)[2][8],
    int& irow, float& sh, float& shprev, float& bl, float& bd,
    const float (&blv)[16], float (&hist)[16])
{
    // prefetch window s+8; plain load -> VGPR, consumed 8/9 steps later;
    // vmcnt never drained (no clobbers, no volatile loads).
    {
        const int r = iclamp(irow, 0, NN - 1);
        buf[P ^ 1][U] = *(const float2*)(Db + ((r << 9) + jb));
        irow += 1;
    }
    const int s = sbase + P * 8 + U;

    // c = 1 (inner column: all-local inputs)
    float nv1;
    {
        constexpr int par  = (U >= 1) ? P : (P ^ 1);
        constexpr int slot = (U >= 1) ? (U - 1) : 7;
        const float d = buf[par][slot].y;
        float wgt = __builtin_amdgcn_exp2f(-L2E * d);
        wgt = ((s - 1) >= tq) ? 0.0f : wgt;        // col jb+1: i = s-1-jb >= 512
        nv1 = wgt * ((r1[1] + r1[0]) + r2[0]);
    }
    hist[P * 8 + U] = nv1;     // lane63's copy published at interval end

    // c = 0 (consumes intra-wave sh/shprev or cross-wave bl/bd)
    float nv0;
    {
        const float lf = (lane == 0) ? bl : sh;
        const float dg = (lane == 0) ? bd : shprev;
        const float d  = buf[P][U].x;
        float wgt = __builtin_amdgcn_exp2f(-L2E * d);
        wgt = (s >= tq) ? 0.0f : wgt;              // col jb: i = s-jb >= 512
        nv0 = wgt * ((r1[0] + lf) + dg);
    }

    r2[0] = r1[0]; r2[1] = r1[1];
    r1[0] = nv0;   r1[1] = nv1;
    bd = bl;
    bl = blv[P * 8 + U];       // writer step s, consumed at step s+1 (static idx)
    shprev = sh;
    sh = dpp_shr1(r1[1]);      // consumed next step's c=0: VALU latency, hidden
}

// Per-wave renorm: rescale own state by 2^-ex, ex = exponent of wave max.
__device__ __forceinline__ void renorm_local(
    float (&r1)[2], float (&r2)[2], float& sh, float& shprev,
    float& bl, float& bd, float& gexp)
{
    float m = __builtin_fmaxf(r1[0], r1[1]);
    m = dpp_fmax<0x111>(m);   // row_shr:1
    m = dpp_fmax<0x112>(m);   // row_shr:2
    m = dpp_fmax<0x114>(m);   // row_shr:4
    m = dpp_fmax<0x118>(m);   // row_shr:8
    m = dpp_fmax<0x142>(m);   // row_bcast:15
    m = dpp_fmax<0x143>(m);   // row_bcast:31 -> lane 63 = wave max
    const int mb = __builtin_amdgcn_readlane(__float_as_int(m), 63);
    const int eb = (mb >> 23) & 255;
    const int ex = (eb > 0 && eb < 255) ? (eb - 127) : 0;  // 0/denorm/inf: hold
    const float rs = __int_as_float((127 - ex) << 23);     // exact 2^-ex
    r1[0] *= rs; r1[1] *= rs; r2[0] *= rs; r2[1] *= rs;
    sh *= rs; shprev *= rs;
    bl *= rs;   // interval-crossing handoffs: compose frames exactly
    bd *= rs;
    gexp += (float)ex;                                     // int-exact in fp32
}

#define S8(PP) \
    dostep<PP,0>(Db,lane,jb,sbase,tq,r1,r2,buf,irow,sh,shprev,bl,bd,blv,hist); \
    dostep<PP,1>(Db,lane,jb,sbase,tq,r1,r2,buf,irow,sh,shprev,bl,bd,blv,hist); \
    dostep<PP,2>(Db,lane,jb,sbase,tq,r1,r2,buf,irow,sh,shprev,bl,bd,blv,hist); \
    dostep<PP,3>(Db,lane,jb,sbase,tq,r1,r2,buf,irow,sh,shprev,bl,bd,blv,hist); \
    dostep<PP,4>(Db,lane,jb,sbase,tq,r1,r2,buf,irow,sh,shprev,bl,bd,blv,hist); \
    dostep<PP,5>(Db,lane,jb,sbase,tq,r1,r2,buf,irow,sh,shprev,bl,bd,blv,hist); \
    dostep<PP,6>(Db,lane,jb,sbase,tq,r1,r2,buf,irow,sh,shprev,bl,bd,blv,hist); \
    dostep<PP,7>(Db,lane,jb,sbase,tq,r1,r2,buf,irow,sh,shprev,bl,bd,blv,hist);

__launch_bounds__(256, 1)
__global__ void softdtw_skew4c(const float* __restrict__ D, float* __restrict__ out) {
    const int b = blockIdx.x;
    const int tid = (int)threadIdx.x;
    const int w = tid >> 6;                  // wave 0..3
    const int lane = tid & 63;
    const int jb = (w << 7) + (lane << 1);   // global column base (2 cols/lane)
    const int tq = jb + NN;                  // junk: s - c >= tq  <=>  i >= NN
    const float* __restrict__ Db = D + (size_t)b * (NN * MM);

    // LDS: ring 4*64 floats (1024 B) + gx 4*2 floats (32 B). Never
    // zero-initialized: for w>0 every consumed slot is written exactly
    // one interval earlier (algebra in header); w==0 garbage is killed
    // by SELECT before any arithmetic.
    __shared__ __align__(16) float ldsF[264];
    const unsigned ldsbase = (unsigned)(size_t)(void*)ldsF;
    const int rw = (w > 0) ? (w - 1) : 0;    // source region (w=0: own, discarded)
    const unsigned rchunk = ldsbase + ((unsigned)rw << 8);
    const unsigned rgx    = ldsbase + 1024u + ((unsigned)rw << 3);
    const unsigned wchunk = ldsbase + ((unsigned)w << 8);
    const unsigned wgx    = ldsbase + 1024u + ((unsigned)w << 3);

    float r1[2] = {0.0f, 0.0f};
    float r2[2] = {0.0f, 0.0f};
    float2 buf[2][8];
    #pragma unroll
    for (int v = 0; v < 8; ++v) buf[1][v] = make_float2(0.0f, 0.0f); // fake cells pre-write
    #pragma unroll
    for (int v = 0; v < 8; ++v) {            // prologue: windows 0..7
        const int r = iclamp(v - jb, 0, NN - 1);
        buf[0][v] = *(const float2*)(Db + ((r << 9) + jb));
    }
    int irow = 8 - jb;                       // row of window s+8 at s=0
    float sh = 0.0f, shprev = 0.0f;
    float bl = 0.0f;                         // left handoff (wave 0: always 0)
    float bd = (w == 0) ? 1.0f : 0.0f;       // seed E(R[0,0]=0)=1 at (0,0); then 0
    float gexp = 0.0f;                       // per-wave frame exponent

    // 67 global intervals; wave w active for k in [w, w+63]
    // (local steps sbase = 16(k-w)). One barrier per interval.
    #pragma unroll 1
    for (int k = 0; k < 67; ++k) {
        // ALL waves: retire LDS writes, then barrier. vmcnt untouched.
        asm volatile("s_waitcnt lgkmcnt(0)\n\ts_barrier");
        const int kw = k - w;
        if (kw < 0 || kw > 63) continue;     // wave-uniform branch
        const int sbase = kw << 4;

        // batch-read neighbor chunk (writer steps sbase..sbase+15, all
        // published at writer interval k-1 under one frame) + that frame.
        f32x4 q0, q1, q2, q3; float gxp;
        {
            const unsigned raddr = rchunk + (((unsigned)sbase & 63u) << 2);
            const unsigned gaddr = rgx + (((unsigned)(k - 1) & 1u) << 2);
            asm volatile(
                "ds_read_b128 %0, %5\n\t"
                "ds_read_b128 %1, %5 offset:16\n\t"
                "ds_read_b128 %2, %5 offset:32\n\t"
                "ds_read_b128 %3, %5 offset:48\n\t"
                "ds_read_b32  %4, %6\n\t"
                "s_waitcnt lgkmcnt(0)"
                : "=&v"(q0), "=&v"(q1), "=&v"(q2), "=&v"(q3), "=&v"(gxp)
                : "v"(raddr), "v"(gaddr));
        }

        renorm_local(r1, r2, sh, shprev, bl, bd, gexp);

        // frame-convert chunk into my (post-renorm) frame; w==0 -> 0 via
        // SELECT (never multiply garbage: NaN*0 = NaN).
        float scale;
        {
            int dlt = (int)(gxp - gexp);     // both int-exact in fp32
            dlt = iclamp(dlt, -126, 126);
            scale = __int_as_float((127 + dlt) << 23);  // exact 2^dlt
        }
        const bool act = (w > 0);
        float blv[16];
        blv[ 0] = act ? q0.x * scale : 0.0f;
        blv[ 1] = act ? q0.y * scale : 0.0f;
        blv[ 2] = act ? q0.z * scale : 0.0f;
        blv[ 3] = act ? q0.w * scale : 0.0f;
        blv[ 4] = act ? q1.x * scale : 0.0f;
        blv[ 5] = act ? q1.y * scale : 0.0f;
        blv[ 6] = act ? q1.z * scale : 0.0f;
        blv[ 7] = act ? q1.w * scale : 0.0f;
        blv[ 8] = act ? q2.x * scale : 0.0f;
        blv[ 9] = act ? q2.y * scale : 0.0f;
        blv[10] = act ? q2.z * scale : 0.0f;
        blv[11] = act ? q2.w * scale : 0.0f;
        blv[12] = act ? q3.x * scale : 0.0f;
        blv[13] = act ? q3.y * scale : 0.0f;
        blv[14] = act ? q3.z * scale : 0.0f;
        blv[15] = act ? q3.w * scale : 0.0f;

        float hist[16];
        hist[15] = 0.0f;   // tail interval leaves step 1023 unwritten;
                           // published but never consumed (reader's
                           // step 1023 doesn't exist). Dead in full
                           // intervals (overwritten at step 15).

        if (kw < 63) {
            S8(0)
            S8(1)
        } else {
            // tail interval: local steps 1008..1022 (15 steps)
            S8(0)
            dostep<1,0>(Db,lane,jb,sbase,tq,r1,r2,buf,irow,sh,shprev,bl,bd,blv,hist);
            dostep<1,1>(Db,lane,jb,sbase,tq,r1,r2,buf,irow,sh,shprev,bl,bd,blv,hist);
            dostep<1,2>(Db,lane,jb,sbase,tq,r1,r2,buf,irow,sh,shprev,bl,bd,blv,hist);
            dostep<1,3>(Db,lane,jb,sbase,tq,r1,r2,buf,irow,sh,shprev,bl,bd,blv,hist);
            dostep<1,4>(Db,lane,jb,sbase,tq,r1,r2,buf,irow,sh,shprev,bl,bd,blv,hist);
            dostep<1,5>(Db,lane,jb,sbase,tq,r1,r2,buf,irow,sh,shprev,bl,bd,blv,hist);
            dostep<1,6>(Db,lane,jb,sbase,tq,r1,r2,buf,irow,sh,shprev,bl,bd,blv,hist);
        }

        // publish chunk + frame (lane63 of waves 0..2); retired by the
        // next interval-top lgkmcnt(0), read after that barrier.
        if (lane == 63 && w < 3) {
            const unsigned waddr = wchunk + (((unsigned)sbase & 63u) << 2);
            const unsigned gaddr = wgx + (((unsigned)k & 1u) << 2);
            const f32x4 h0 = {hist[ 0], hist[ 1], hist[ 2], hist[ 3]};
            const f32x4 h1 = {hist[ 4], hist[ 5], hist[ 6], hist[ 7]};
            const f32x4 h2 = {hist[ 8], hist[ 9], hist[10], hist[11]};
            const f32x4 h3 = {hist[12], hist[13], hist[14], hist[15]};
            asm volatile(
                "ds_write_b128 %0, %2\n\t"
                "ds_write_b128 %0, %3 offset:16\n\t"
                "ds_write_b128 %0, %4 offset:32\n\t"
                "ds_write_b128 %0, %5 offset:48\n\t"
                "ds_write_b32  %1, %6"
                :: "v"(waddr), "v"(gaddr),
                   "v"(h0), "v"(h1), "v"(h2), "v"(h3), "v"(gexp));
        }
    }

    // final cell (511,511): wave 3, lane 63, c=1 at local step 1022.
    // E_true = r1[1] * 2^gexp;  R = -(log2(r1[1]) + gexp) * ln2
    if (w == 3 && lane == 63) {
        out[b] = -(__builtin_amdgcn_logf(r1[1]) + gexp) * LN2;
    }
}

extern "C" void kernel_launch(void* const* d_in, const int* in_sizes, int n_in,
                              void* d_out, int out_size, void* d_ws, size_t ws_size,
                              hipStream_t stream) {
    const float* D = (const float*)d_in[0];
    float* out = (float*)d_out;
    softdtw_skew4c<<<BB, 256, 0, stream>>>(D, out);
}

// Round 6
// 320.222 us; speedup vs baseline: 2.1788x; 1.0262x over previous
//
#include <hip/hip_runtime.h>

// Soft-DTW forward, B=128, N=M=512, gamma=1.0, fp32.
// ROUND-15: 2 waves x 4 cols/lane (128 thr/block), skew-16 ring pipeline.
// R14 post-mortem (196us, 440cy/step): VGPR=56 < the ~84 needed -> blv[16]
// + hist[16] were in SCRATCH. The per-step scratch blv load sits behind the
// step's global load in the FIFO vmcnt queue; consuming bl next step forces
// the queue down past the previous step's global load -> ~L/2 latency
// exposure per step (the R8/R10 poison, 4th door). On top: address-divergent
// gather floor — 4 waves x 64 lanes x 8B loads on 2KB-strided rows = 256
// distinct-line requests/step/CU through the TA, with L1 thrash (36KB band
// > 32KB L1). Model fits R9 (1 wave, 128 req + 140cy issue = 486cy) and
// R14 (256 req + spill coupling = 440cy).
// Fixes, structural:
//   - 4 cols/lane -> ONE float4 (16B) load per step: 128 req/step/CU (2x
//     fewer), every 64B line fetched once; issue split across 2 SIMDs.
//   - hist[] GONE: lane63 of wave0 publishes its boundary nv3 with one
//     exec-masked ds_write_b32 per step (volatile asm, retired by the
//     interval-end lgkmcnt(0); same write(k) -> barrier -> read(k+1)
//     separation as R14's batched publish).
//   - blv[] -> 4 named f32x4 with static component access only.
// Carried over verified (absmax=0 in R12/R14): skew: wave1 runs 16
// diagonals behind wave0; 64-slot LDS ring, chunk [sbase..sbase+15] read
// at interval top with 4x ds_read_b128 + frame gexp + lgkmcnt(0) in ONE
// volatile asm; ONE "lgkmcnt(0); s_barrier" per 16-step interval (vmcnt
// NEVER drained in the loop); per-wave renorm every 16 steps (DPP
// row_shr/bcast ladder + readlane63); frame conversion by exact pow2
// scale, w==0 garbage killed by SELECT; exp-domain DP (E=e^-R,
// nv=wg*(up+left+diag), wg=exp2(-d*log2e)); junk-at-consume
// (junk <=> s-c >= jb+512); pre-active cells 0 via zeroed state (+ slots
// 13..15 zero-init: read before first write at T=0..2).
// Slot algebra (re-derived for 4 cols): window v (= D row v-jb, cols
// jb..jb+3) lives at buf[v & 15]; cell c at diagonal s consumes component
// c of window s-c -> buf[(16+T-c)&15] at T=s-sbase. Write at step T goes
// to buf[(T+8)&15] (window sbase+T+8); old content (window sbase+T-8)
// was last consumed at step T-5 — dead. Boundary: writer wave0 lane63
// col 255 = its nv3 at diagonal s -> ring[s&63]; reader wave1 lane0
// col 256 at diagonal m consumes left = boundary(m-1) via bl (loaded end
// of step m-1), diag = boundary(m-2) via bd. Ring slot rewritten 4
// intervals after write; reader reads slots 16 apart (mod 64) from
// writer's same-interval writes.

#define BB 128
#define NN 512
#define MM 512
#define L2E 1.4426950408889634f
#define LN2 0.6931471805599453f

typedef float f32x4 __attribute__((ext_vector_type(4)));

__device__ __forceinline__ int iclamp(int x, int lo, int hi) {
    return x < lo ? lo : (x > hi ? hi : x);
}

template<int CTRL>
__device__ __forceinline__ float dpp_fmax(float v) {
    const int s = __builtin_amdgcn_update_dpp(
        __float_as_int(v), __float_as_int(v), CTRL, 0xF, 0xF, false);
    return __builtin_fmaxf(v, __int_as_float(s));
}

// lane k <- lane k-1 (whole wave, wave_shr:1), VALU-speed; lane 0 keeps
// its old value (unused there: lane 0's c=0 selects bl/bd, not sh).
__device__ __forceinline__ float dpp_shr1(float v) {
    const int s = __builtin_amdgcn_update_dpp(
        __float_as_int(v), __float_as_int(v), 0x138, 0xF, 0xF, false);
    return __int_as_float(s);
}

// One DP step: 4 cells (cols jb..jb+3) on diagonal s = sbase + T.
// Pure VALU + 1 plain float4 global load (+1 exec-masked ds_write for
// wave0 lane63). No memory clobbers anywhere.
template<int T>
__device__ __forceinline__ void dostep(
    const float* __restrict__ Db, const int lane, const bool wpub,
    const int jb, const int sbase, const int tq,
    float (&r1)[4], float (&r2)[4], float4 (&buf)[16],
    int& irow, float& sh, float& shprev, float& bl, float& bd,
    const f32x4 (&bv)[4], const unsigned wrA)
{
    // prefetch window sbase+T+8; plain load -> VGPR, consumed 8..11 steps
    // later; vmcnt never drained (no clobbers, no volatile loads).
    {
        const int r = iclamp(irow, 0, NN - 1);
        buf[(T + 8) & 15] = *(const float4*)(Db + ((r << 9) + jb));
        irow += 1;
    }
    const int s = sbase + T;

    float nv0, nv1, nv2, nv3;
    {   // c = 3 (lane-local)
        constexpr int i3 = (16 + T - 3) & 15;
        const float d = buf[i3].w;
        float wg = __builtin_amdgcn_exp2f(-L2E * d);
        wg = ((s - 3) >= tq) ? 0.0f : wg;          // i = s-3-jb >= 512
        nv3 = wg * ((r1[3] + r1[2]) + r2[2]);
    }
    {   // c = 2
        constexpr int i2 = (16 + T - 2) & 15;
        const float d = buf[i2].z;
        float wg = __builtin_amdgcn_exp2f(-L2E * d);
        wg = ((s - 2) >= tq) ? 0.0f : wg;
        nv2 = wg * ((r1[2] + r1[1]) + r2[1]);
    }
    {   // c = 1
        constexpr int i1 = (16 + T - 1) & 15;
        const float d = buf[i1].y;
        float wg = __builtin_amdgcn_exp2f(-L2E * d);
        wg = ((s - 1) >= tq) ? 0.0f : wg;
        nv1 = wg * ((r1[1] + r1[0]) + r2[0]);
    }
    // boundary publish (wave0 lane63 only): ring[s&63] <- nv3. Retired by
    // the interval-end lgkmcnt(0); read by wave1 one interval later.
    if (wpub)
        asm volatile("ds_write_b32 %0, %1 offset:%2"
                     :: "v"(wrA), "v"(nv3), "n"(T * 4));
    {   // c = 0 (consumes intra-wave sh/shprev or cross-wave bl/bd)
        constexpr int i0 = T & 15;
        const float d = buf[i0].x;
        const float lf = (lane == 0) ? bl : sh;
        const float dg = (lane == 0) ? bd : shprev;
        float wg = __builtin_amdgcn_exp2f(-L2E * d);
        wg = (s >= tq) ? 0.0f : wg;
        nv0 = wg * ((r1[0] + lf) + dg);
    }

    r2[0] = r1[0]; r2[1] = r1[1]; r2[2] = r1[2]; r2[3] = r1[3];
    r1[0] = nv0;   r1[1] = nv1;   r1[2] = nv2;   r1[3] = nv3;
    bd = bl;
    bl = bv[T >> 2][T & 3];    // boundary(s), consumed at step s+1 (static idx)
    shprev = sh;
    sh = dpp_shr1(nv3);        // neighbor handoff, consumed next step
}

// Per-wave renorm: rescale own state by 2^-ex, ex = exponent of wave max.
__device__ __forceinline__ void renorm_local(
    float (&r1)[4], float (&r2)[4], float& sh, float& shprev,
    float& bl, float& bd, float& gexp)
{
    float m = __builtin_fmaxf(__builtin_fmaxf(r1[0], r1[1]),
                              __builtin_fmaxf(r1[2], r1[3]));
    m = dpp_fmax<0x111>(m);   // row_shr:1
    m = dpp_fmax<0x112>(m);   // row_shr:2
    m = dpp_fmax<0x114>(m);   // row_shr:4
    m = dpp_fmax<0x118>(m);   // row_shr:8
    m = dpp_fmax<0x142>(m);   // row_bcast:15
    m = dpp_fmax<0x143>(m);   // row_bcast:31 -> lane 63 = wave max
    const int mb = __builtin_amdgcn_readlane(__float_as_int(m), 63);
    const int eb = (mb >> 23) & 255;
    const int ex = (eb > 0 && eb < 255) ? (eb - 127) : 0;  // 0/denorm/inf: hold
    const float rs = __int_as_float((127 - ex) << 23);     // exact 2^-ex
    r1[0] *= rs; r1[1] *= rs; r1[2] *= rs; r1[3] *= rs;
    r2[0] *= rs; r2[1] *= rs; r2[2] *= rs; r2[3] *= rs;
    sh *= rs; shprev *= rs;
    bl *= rs;   // interval-crossing handoffs: compose frames exactly
    bd *= rs;
    gexp += (float)ex;                                     // int-exact in fp32
}

#define DSTEP(T) dostep<T>(Db,lane,wpub,jb,sbase,tq,r1,r2,buf,irow,sh,shprev,bl,bd,bv,wrA);

__launch_bounds__(128, 1)
__global__ void softdtw_skew2(const float* __restrict__ D, float* __restrict__ out) {
    const int b = blockIdx.x;
    const int tid = (int)threadIdx.x;
    const int w = tid >> 6;                  // wave 0..1
    const int lane = tid & 63;
    const int jb = (w << 8) + (lane << 2);   // global column base (4 cols/lane)
    const int tq = jb + NN;                  // junk: s - c >= tq  <=>  i >= NN
    const bool wpub = (w == 0) && (lane == 63);
    const float* __restrict__ Db = D + (size_t)b * (NN * MM);

    // LDS: ring 64 slots (256B, one boundary) + gx 2 parity slots (8B).
    // Never zero-initialized: every slot wave1 consumes was written one
    // interval earlier; wave0's reads of this region are killed by SELECT.
    __shared__ __align__(16) float ldsF[66];
    const unsigned ldsbase = (unsigned)(size_t)(void*)ldsF;
    const unsigned ringb = ldsbase;
    const unsigned gxb   = ldsbase + 256u;

    float r1[4] = {0.0f, 0.0f, 0.0f, 0.0f};
    float r2[4] = {0.0f, 0.0f, 0.0f, 0.0f};
    float4 buf[16];
    // slots 13..15 are read (pre-active fake cells, T=0..2) before their
    // first write at T=5..7 — keep finite so wg*0sums stays 0.
    buf[13] = make_float4(0.f, 0.f, 0.f, 0.f);
    buf[14] = make_float4(0.f, 0.f, 0.f, 0.f);
    buf[15] = make_float4(0.f, 0.f, 0.f, 0.f);
    #pragma unroll
    for (int v = 0; v < 8; ++v) {            // prologue: windows 0..7 -> slots 0..7
        const int r = iclamp(v - jb, 0, NN - 1);
        buf[v] = *(const float4*)(Db + ((r << 9) + jb));
    }
    int irow = 8 - jb;                       // row of window s+8 at s=0
    float sh = 0.0f, shprev = 0.0f;
    float bl = 0.0f;                         // cross-wave left (wave0: always 0)
    float bd = (w == 0) ? 1.0f : 0.0f;       // seed E(R[0,0]=0)=1 at (0,0); then 0
    float gexp = 0.0f;                       // per-wave frame exponent

    // 65 global intervals; wave w active for k in [w, w+63]
    // (local diagonals sbase = 16(k-w)). One barrier per interval.
    #pragma unroll 1
    for (int k = 0; k < 65; ++k) {
        // BOTH waves: retire LDS writes, then barrier. vmcnt untouched.
        asm volatile("s_waitcnt lgkmcnt(0)\n\ts_barrier");
        const int kw = k - w;
        if (kw < 0 || kw > 63) continue;     // wave-uniform branch
        const int sbase = kw << 4;

        // batch-read boundary chunk (diagonals sbase..sbase+15, written by
        // wave0 during interval k-1 under one frame) + that frame.
        f32x4 q0, q1, q2, q3; float gxp;
        {
            const unsigned raddr = ringb + (((unsigned)sbase & 63u) << 2);
            const unsigned gaddr = gxb + (((unsigned)(k - 1) & 1u) << 2);
            asm volatile(
                "ds_read_b128 %0, %5\n\t"
                "ds_read_b128 %1, %5 offset:16\n\t"
                "ds_read_b128 %2, %5 offset:32\n\t"
                "ds_read_b128 %3, %5 offset:48\n\t"
                "ds_read_b32  %4, %6\n\t"
                "s_waitcnt lgkmcnt(0)"
                : "=&v"(q0), "=&v"(q1), "=&v"(q2), "=&v"(q3), "=&v"(gxp)
                : "v"(raddr), "v"(gaddr));
        }

        renorm_local(r1, r2, sh, shprev, bl, bd, gexp);

        // publish my frame for this interval's ring writes (parity k&1;
        // read by wave1 at interval k+1; overwritten at k+2).
        if (wpub) {
            const unsigned ga = gxb + (((unsigned)k & 1u) << 2);
            asm volatile("ds_write_b32 %0, %1" :: "v"(ga), "v"(gexp));
        }

        // frame-convert chunk into my (post-renorm) frame; w==0 -> 0 via
        // SELECT (never multiply garbage into live values).
        float scale;
        {
            int dlt = (int)(gxp - gexp);     // both int-exact in fp32
            dlt = iclamp(dlt, -126, 126);
            scale = __int_as_float((127 + dlt) << 23);  // exact 2^dlt
        }
        const bool act = (w > 0);
        const f32x4 zz = {0.0f, 0.0f, 0.0f, 0.0f};
        f32x4 bv[4];
        bv[0] = act ? q0 * scale : zz;
        bv[1] = act ? q1 * scale : zz;
        bv[2] = act ? q2 * scale : zz;
        bv[3] = act ? q3 * scale : zz;

        const unsigned wrA = ringb + (((unsigned)sbase & 63u) << 2);

        if (kw < 63) {
            DSTEP(0)  DSTEP(1)  DSTEP(2)  DSTEP(3)
            DSTEP(4)  DSTEP(5)  DSTEP(6)  DSTEP(7)
            DSTEP(8)  DSTEP(9)  DSTEP(10) DSTEP(11)
            DSTEP(12) DSTEP(13) DSTEP(14) DSTEP(15)
        } else {
            // tail interval: diagonals 1008..1022 (15 steps)
            DSTEP(0)  DSTEP(1)  DSTEP(2)  DSTEP(3)
            DSTEP(4)  DSTEP(5)  DSTEP(6)  DSTEP(7)
            DSTEP(8)  DSTEP(9)  DSTEP(10) DSTEP(11)
            DSTEP(12) DSTEP(13) DSTEP(14)
        }
    }

    // final cell (511,511): wave1, lane63, c=3 at diagonal 1022.
    // E_true = r1[3] * 2^gexp;  R = -(log2(r1[3]) + gexp) * ln2
    if (w == 1 && lane == 63) {
        out[b] = -(__builtin_amdgcn_logf(r1[3]) + gexp) * LN2;
    }
}

extern "C" void kernel_launch(void* const* d_in, const int* in_sizes, int n_in,
                              void* d_out, int out_size, void* d_ws, size_t ws_size,
                              hipStream_t stream) {
    const float* D = (const float*)d_in[0];
    float* out = (float*)d_out;
    softdtw_skew2<<<BB, 128, 0, stream>>>(D, out);
}